// Round 5
// baseline (353.644 us; speedup 1.0000x reference)
//
#include <hip/hip_runtime.h>
#include <hip/hip_bf16.h>

#define B_ 4
#define T_ 2048
#define C_ 1024
#define H_ 16
#define D_ 64
#define N3_ 3072
#define M_ (B_*T_)

typedef __bf16 bf16x8 __attribute__((ext_vector_type(8)));
typedef float f32x4 __attribute__((ext_vector_type(4)));

__device__ __forceinline__ unsigned short f2bf(float f){
  __bf16 h = (__bf16)f;              // RNE fptrunc -> v_cvt on gfx950
  return __builtin_bit_cast(unsigned short, h);
}
__device__ __forceinline__ unsigned int pk2(float a, float b){
  return (unsigned int)f2bf(a) | ((unsigned int)f2bf(b)<<16);
}
// async global->LDS, 16B per lane; LDS dest = base + lane*16 (wave-uniform base)
__device__ __forceinline__ void gload_lds16(const unsigned short* g, unsigned short* l){
  __builtin_amdgcn_global_load_lds(
      (const __attribute__((address_space(1))) void*)g,
      (__attribute__((address_space(3))) void*)l, 16, 0, 0);
}

// ---------------- x fp32 -> bf16 one-time convert ---------------------------
__global__ __launch_bounds__(256) void x_cvt(
    const float* __restrict__ X, unsigned short* __restrict__ Xb)
{
  const size_t i = ((size_t)blockIdx.x*256 + threadIdx.x)*8;
  float4 f0 = *(const float4*)(X+i);
  float4 f1 = *(const float4*)(X+i+4);
  uint4 w = make_uint4(pk2(f0.x,f0.y), pk2(f0.z,f0.w), pk2(f1.x,f1.y), pk2(f1.z,f1.w));
  *(uint4*)(Xb+i) = w;
}

// ---------------- transpose + fp32->bf16 convert: src[K][N] -> dst[N][K] ----
__global__ __launch_bounds__(256) void transpose_cvt(
    const float* __restrict__ src, unsigned short* __restrict__ dst, int K, int N)
{
  __shared__ float tile[32][33];
  const int tx = threadIdx.x & 31, ty = threadIdx.x >> 5; // 32 x 8
  const int nt = blockIdx.x * 32, kt = blockIdx.y * 32;
  #pragma unroll
  for (int i=0;i<32;i+=8) tile[ty+i][tx] = src[(size_t)(kt+ty+i)*N + nt+tx];
  __syncthreads();
  #pragma unroll
  for (int i=0;i<32;i+=8) dst[(size_t)(nt+ty+i)*K + kt+tx] = f2bf(tile[tx][ty+i]);
}

// ---------------- QKV GEMM (m97-style global_load_lds staging) --------------
__global__ __launch_bounds__(256) void qkv_gemm(
    const unsigned short* __restrict__ Xb, const unsigned short* __restrict__ Wt,
    const float* __restrict__ bias,
    unsigned short* __restrict__ Qb, unsigned short* __restrict__ Kb,
    unsigned short* __restrict__ Vt)
{
  __shared__ __align__(16) unsigned short As[128][32];
  __shared__ __align__(16) unsigned short Bs[128][32];
  const int tid = threadIdx.x;
  const int m0 = blockIdx.y*128, n0 = blockIdx.x*128;
  const int wv = tid>>6, lane = tid&63, lm = lane&15, lq = lane>>4;
  const int wr = wv>>1, wc = wv&1;
  f32x4 acc[4][4] = {};
  const int schunk = (lane&3) ^ ((lane>>3)&3);
  const unsigned short* gA = Xb + (size_t)(m0 + wv*32 + (lane>>2))*C_ + schunk*8;
  const unsigned short* gB = Wt + (size_t)(n0 + wv*32 + (lane>>2))*C_ + schunk*8;
  unsigned short* lA0 = &As[wv*32][0];
  unsigned short* lA1 = &As[wv*32+16][0];
  unsigned short* lB0 = &Bs[wv*32][0];
  unsigned short* lB1 = &Bs[wv*32+16][0];
  const int rkey = (lm>>1)&3;
  for (int k0=0;k0<C_;k0+=32){
    __syncthreads();
    gload_lds16(gA + k0,            lA0);
    gload_lds16(gA + 16*C_ + k0,    lA1);
    gload_lds16(gB + k0,            lB0);
    gload_lds16(gB + 16*C_ + k0,    lB1);
    __syncthreads();
    bf16x8 a[4], b[4];
    #pragma unroll
    for (int mt=0;mt<4;mt++) a[mt] = *(const bf16x8*)&As[wr*64+mt*16+lm][(lq^rkey)*8];
    #pragma unroll
    for (int nt=0;nt<4;nt++) b[nt] = *(const bf16x8*)&Bs[wc*64+nt*16+lm][(lq^rkey)*8];
    #pragma unroll
    for (int mt=0;mt<4;mt++)
      #pragma unroll
      for (int nt=0;nt<4;nt++)
        acc[mt][nt] = __builtin_amdgcn_mfma_f32_16x16x32_bf16(a[mt], b[nt], acc[mt][nt], 0,0,0);
  }
  const int sel = n0>>10;  // block-uniform: 0=Q,1=K,2=V
  const float qsc = (sel==0) ? 0.18033688f : 1.0f;  // 0.125*log2(e) folded into Q
  #pragma unroll
  for (int mt=0;mt<4;mt++){
    const int grow = m0 + wr*64 + mt*16 + lq*4;
    const int bb = grow>>11, tt0 = grow&2047;
    #pragma unroll
    for (int nt=0;nt<4;nt++){
      const int gcol = n0 + wc*64 + nt*16 + lm;
      const int hh = (gcol>>6)&15, dd = gcol&63;
      const float bv = bias[gcol];
      if (sel==2){
        ushort4 pv;
        pv.x = f2bf(acc[mt][nt][0] + bv);
        pv.y = f2bf(acc[mt][nt][1] + bv);
        pv.z = f2bf(acc[mt][nt][2] + bv);
        pv.w = f2bf(acc[mt][nt][3] + bv);
        *(ushort4*)&Vt[ ((size_t)(bb*H_+hh)*D_ + dd)*T_ + tt0 ] = pv;
      } else {
        unsigned short* dst = (sel==0) ? Qb : Kb;
        #pragma unroll
        for (int r=0;r<4;r++)
          dst[ ((size_t)(bb*H_+hh)*T_ + tt0 + r)*D_ + dd ] = f2bf((acc[mt][nt][r] + bv)*qsc);
      }
    }
  }
}

// ---------------- flash attention -------------------------------------------
// 16KB LDS (K-buffer shared with P), async K/V staging w/ XOR swizzle,
// O computed transposed (operand swap) for vectorized epilogue.
// Grid flat 2048: bh = id&63 (XCD locality), qi = 31-(id>>6) (heavy first).
__global__ __launch_bounds__(256, 8) void flash_attn(
    const unsigned short* __restrict__ Qb, const unsigned short* __restrict__ Kb,
    const unsigned short* __restrict__ Vt, unsigned short* __restrict__ Yb)
{
  __shared__ __align__(16) unsigned short KPs[64][64]; // K tile (swizzled); reused for P
  __shared__ __align__(16) unsigned short Vs[64][64];  // V^T tile (swizzled)
  const int tid = threadIdx.x;
  const int wv = tid>>6, lane = tid&63, lm = lane&15, lq = lane>>4;
  const int id = (int)blockIdx.x;
  const int bh = id & 63;
  const int qi = 31 - (id >> 6);
  const int qbase = qi*64;
  const unsigned short* Qh = Qb + (size_t)bh*T_*D_;
  const unsigned short* Kh = Kb + (size_t)bh*T_*D_;
  const unsigned short* Vh = Vt + (size_t)bh*D_*T_;
  bf16x8 aq[2];
  {
    const int q = qbase + wv*16 + lm;
    aq[0] = *(const bf16x8*)&Qh[(size_t)q*D_ + lq*8];
    aq[1] = *(const bf16x8*)&Qh[(size_t)q*D_ + 32 + lq*8];
  }
  f32x4 o[4] = {};
  float l_r[4] = {0.f,0.f,0.f,0.f};
  // staging: wave wv covers rows [wv*16, wv*16+16) in two 8-row DMA issues;
  // lane -> row wv*16 + 8*is + (lane>>3), stored chunk lane&7, source chunk
  // (lane&7)^(row&7)
  const int srl = lane>>3;
  const int sc  = (lane&7) ^ srl;
  const unsigned short* kg = Kh + (size_t)(wv*16 + srl)*D_ + sc*8;
  const unsigned short* vg = Vh + (size_t)(wv*16 + srl)*T_ + sc*8;
  unsigned short* lk0 = &KPs[wv*16][0];
  unsigned short* lk1 = &KPs[wv*16+8][0];
  unsigned short* lv0 = &Vs[wv*16][0];
  unsigned short* lv1 = &Vs[wv*16+8][0];
  const int keyR = lm&7;   // read swizzle key for LDS rows ...*16+lm
  for (int j=0;j<=qi;j++){
    __syncthreads();                       // prev iter P/V reads done
    gload_lds16(kg + (size_t)(j*64  )*D_, lk0);
    gload_lds16(kg + (size_t)(j*64+8)*D_, lk1);
    gload_lds16(vg + j*64,                lv0);
    gload_lds16(vg + 8*T_ + j*64,         lv1);
    __syncthreads();                       // DMA drained (vmcnt) + visible
    // S = Q K^T  (per wave: 16 q rows x 64 keys)
    f32x4 s[4] = {};
    #pragma unroll
    for (int nt=0;nt<4;nt++){
      bf16x8 bk0 = *(const bf16x8*)&KPs[nt*16+lm][((lq  )^keyR)*8];
      bf16x8 bk1 = *(const bf16x8*)&KPs[nt*16+lm][((lq+4)^keyR)*8];
      s[nt] = __builtin_amdgcn_mfma_f32_16x16x32_bf16(aq[0], bk0, s[nt], 0,0,0);
      s[nt] = __builtin_amdgcn_mfma_f32_16x16x32_bf16(aq[1], bk1, s[nt], 0,0,0);
    }
    // p = exp2(s) (Q pre-scaled); causal mask only on diagonal tile
    if (j==qi){
      const int qrow0 = wv*16 + lq*4;
      #pragma unroll
      for (int nt=0;nt<4;nt++){
        const int col = nt*16+lm;
        #pragma unroll
        for (int r=0;r<4;r++)
          s[nt][r] = (col <= qrow0+r) ? exp2f(s[nt][r]) : 0.f;
      }
    } else {
      #pragma unroll
      for (int nt=0;nt<4;nt++)
        #pragma unroll
        for (int r=0;r<4;r++)
          s[nt][r] = exp2f(s[nt][r]);
    }
    #pragma unroll
    for (int r=0;r<4;r++)
      l_r[r] += (s[0][r]+s[1][r]) + (s[2][r]+s[3][r]);
    __syncthreads();                       // all QK^T reads of K done
    // P -> LDS (C layout, swizzled chunks); rows [16wv,16wv+16) wave-local
    #pragma unroll
    for (int nt=0;nt<4;nt++)
      #pragma unroll
      for (int r=0;r<4;r++){
        const int row = wv*16 + lq*4 + r;
        const int ch  = (2*nt + (lm>>3)) ^ (row&7);
        KPs[row][ch*8 + (lm&7)] = f2bf(s[nt][r]);
      }
    // O^T += V^T P^T : mfma(A=V-frag, B=P-frag) -> D[m=d][n=q]
    #pragma unroll
    for (int kc=0;kc<2;kc++){
      bf16x8 ap = *(const bf16x8*)&KPs[wv*16+lm][((kc*4+lq)^keyR)*8];
      #pragma unroll
      for (int dt=0;dt<4;dt++){
        bf16x8 bv = *(const bf16x8*)&Vs[dt*16+lm][((kc*4+lq)^keyR)*8];
        o[dt] = __builtin_amdgcn_mfma_f32_16x16x32_bf16(bv, ap, o[dt], 0,0,0);
      }
    }
  }
  // l: reduce across 16 lm-lanes, then broadcast to transposed layout (q=lm)
  #pragma unroll
  for (int r=0;r<4;r++){
    float rs = l_r[r];
    rs += __shfl_xor(rs,1); rs += __shfl_xor(rs,2);
    rs += __shfl_xor(rs,4); rs += __shfl_xor(rs,8);
    l_r[r] = rs;
  }
  const int srcl = (lm>>2)<<4;  // lane holding row q=lm (lq_src=lm>>2, any lm)
  float lv0v = __shfl(l_r[0], srcl);
  float lv1v = __shfl(l_r[1], srcl);
  float lv2v = __shfl(l_r[2], srcl);
  float lv3v = __shfl(l_r[3], srcl);
  const int rr = lm&3;
  float linv = (rr==0) ? lv0v : (rr==1) ? lv1v : (rr==2) ? lv2v : lv3v;
  linv = 1.0f/linv;
  const int bb = bh>>4, hh = bh&15;
  const int q = qbase + wv*16 + lm;
  #pragma unroll
  for (int dt=0;dt<4;dt++){
    ushort4 y;
    y.x = f2bf(o[dt][0]*linv);
    y.y = f2bf(o[dt][1]*linv);
    y.z = f2bf(o[dt][2]*linv);
    y.w = f2bf(o[dt][3]*linv);
    *(ushort4*)&Yb[ ((size_t)bb*T_ + q)*C_ + hh*64 + dt*16 + lq*4 ] = y;
  }
}

// ---------------- proj GEMM (m97-style): Yb x Wpt^T -> fp32 out + bias ------
__global__ __launch_bounds__(256) void proj_gemm(
    const unsigned short* __restrict__ Yb, const unsigned short* __restrict__ Wt,
    const float* __restrict__ bias, float* __restrict__ Out)
{
  __shared__ __align__(16) unsigned short As[128][32];
  __shared__ __align__(16) unsigned short Bs[128][32];
  const int tid = threadIdx.x;
  const int m0 = blockIdx.y*128, n0 = blockIdx.x*128;
  const int wv = tid>>6, lane = tid&63, lm = lane&15, lq = lane>>4;
  const int wr = wv>>1, wc = wv&1;
  f32x4 acc[4][4] = {};
  const int schunk = (lane&3) ^ ((lane>>3)&3);
  const unsigned short* gA = Yb + (size_t)(m0 + wv*32 + (lane>>2))*C_ + schunk*8;
  const unsigned short* gB = Wt + (size_t)(n0 + wv*32 + (lane>>2))*C_ + schunk*8;
  unsigned short* lA0 = &As[wv*32][0];
  unsigned short* lA1 = &As[wv*32+16][0];
  unsigned short* lB0 = &Bs[wv*32][0];
  unsigned short* lB1 = &Bs[wv*32+16][0];
  const int rkey = (lm>>1)&3;
  for (int k0=0;k0<C_;k0+=32){
    __syncthreads();
    gload_lds16(gA + k0,            lA0);
    gload_lds16(gA + 16*C_ + k0,    lA1);
    gload_lds16(gB + k0,            lB0);
    gload_lds16(gB + 16*C_ + k0,    lB1);
    __syncthreads();
    bf16x8 a[4], b[4];
    #pragma unroll
    for (int mt=0;mt<4;mt++) a[mt] = *(const bf16x8*)&As[wr*64+mt*16+lm][(lq^rkey)*8];
    #pragma unroll
    for (int nt=0;nt<4;nt++) b[nt] = *(const bf16x8*)&Bs[wc*64+nt*16+lm][(lq^rkey)*8];
    #pragma unroll
    for (int mt=0;mt<4;mt++)
      #pragma unroll
      for (int nt=0;nt<4;nt++)
        acc[mt][nt] = __builtin_amdgcn_mfma_f32_16x16x32_bf16(a[mt], b[nt], acc[mt][nt], 0,0,0);
  }
  #pragma unroll
  for (int mt=0;mt<4;mt++){
    const int grow = m0 + wr*64 + mt*16 + lq*4;
    #pragma unroll
    for (int nt=0;nt<4;nt++){
      const int gcol = n0 + wc*64 + nt*16 + lm;
      const float bv = bias[gcol];
      #pragma unroll
      for (int r=0;r<4;r++)
        Out[(size_t)(grow+r)*C_ + gcol] = acc[mt][nt][r] + bv;
    }
  }
}

extern "C" void kernel_launch(void* const* d_in, const int* in_sizes, int n_in,
                              void* d_out, int out_size, void* d_ws, size_t ws_size,
                              hipStream_t stream)
{
  const float* x      = (const float*)d_in[0];
  const float* W_attn = (const float*)d_in[1];
  const float* b_attn = (const float*)d_in[2];
  const float* W_proj = (const float*)d_in[3];
  const float* b_proj = (const float*)d_in[4];
  float* out = (float*)d_out;

  unsigned short* Wat = (unsigned short*)d_ws;            // [3072][1024] bf16
  unsigned short* Wpt = Wat + (size_t)N3_*C_;             // [1024][1024] bf16
  unsigned short* Xb  = Wpt + (size_t)C_*C_;              // [M,1024]  bf16
  unsigned short* Qb  = Xb  + (size_t)M_*C_;              // [B,H,T,D] bf16 (pre-scaled)
  unsigned short* Kb  = Qb  + (size_t)M_*C_;              // [B,H,T,D] bf16
  unsigned short* Vt  = Kb  + (size_t)M_*C_;              // [B,H,D,T] bf16
  unsigned short* Yb  = Vt  + (size_t)M_*C_;              // [M,1024]  bf16
  (void)ws_size; (void)in_sizes; (void)n_in; (void)out_size;

  x_cvt        <<<dim3(M_*C_/2048),      256, 0, stream>>>(x, Xb);
  transpose_cvt<<<dim3(N3_/32, C_/32),   256, 0, stream>>>(W_attn, Wat, C_, N3_);
  transpose_cvt<<<dim3(C_/32,  C_/32),   256, 0, stream>>>(W_proj, Wpt, C_, C_);
  qkv_gemm     <<<dim3(N3_/128, M_/128), 256, 0, stream>>>(Xb, Wat, b_attn, Qb, Kb, Vt);
  flash_attn   <<<dim3(2048),            256, 0, stream>>>(Qb, Kb, Vt, Yb);
  proj_gemm    <<<dim3(C_/128, M_/128),  256, 0, stream>>>(Yb, Wpt, b_proj, out);
}

// Round 6
// 259.762 us; speedup vs baseline: 1.3614x; 1.3614x over previous
//
#include <hip/hip_runtime.h>
#include <hip/hip_bf16.h>

#define B_ 4
#define T_ 2048
#define C_ 1024
#define H_ 16
#define D_ 64
#define N3_ 3072
#define M_ (B_*T_)

typedef __bf16 bf16x8 __attribute__((ext_vector_type(8)));
typedef float f32x4 __attribute__((ext_vector_type(4)));

__device__ __forceinline__ unsigned short f2bf(float f){
  __bf16 h = (__bf16)f;              // RNE fptrunc -> v_cvt on gfx950
  return __builtin_bit_cast(unsigned short, h);
}
__device__ __forceinline__ unsigned int pk2(float a, float b){
  return (unsigned int)f2bf(a) | ((unsigned int)f2bf(b)<<16);
}
// async global->LDS, 16B per lane; LDS dest = base + lane*16 (wave-uniform base)
__device__ __forceinline__ void gload_lds16(const unsigned short* g, unsigned short* l){
  __builtin_amdgcn_global_load_lds(
      (const __attribute__((address_space(1))) void*)g,
      (__attribute__((address_space(3))) void*)l, 16, 0, 0);
}

// ---------------- x fp32 -> bf16 one-time convert ---------------------------
__global__ __launch_bounds__(256) void x_cvt(
    const float* __restrict__ X, unsigned short* __restrict__ Xb)
{
  const size_t i = ((size_t)blockIdx.x*256 + threadIdx.x)*8;
  float4 f0 = *(const float4*)(X+i);
  float4 f1 = *(const float4*)(X+i+4);
  uint4 w = make_uint4(pk2(f0.x,f0.y), pk2(f0.z,f0.w), pk2(f1.x,f1.y), pk2(f1.z,f1.w));
  *(uint4*)(Xb+i) = w;
}

// ---------------- transpose + fp32->bf16 convert: src[K][N] -> dst[N][K] ----
__global__ __launch_bounds__(256) void transpose_cvt(
    const float* __restrict__ src, unsigned short* __restrict__ dst, int K, int N)
{
  __shared__ float tile[32][33];
  const int tx = threadIdx.x & 31, ty = threadIdx.x >> 5; // 32 x 8
  const int nt = blockIdx.x * 32, kt = blockIdx.y * 32;
  #pragma unroll
  for (int i=0;i<32;i+=8) tile[ty+i][tx] = src[(size_t)(kt+ty+i)*N + nt+tx];
  __syncthreads();
  #pragma unroll
  for (int i=0;i<32;i+=8) dst[(size_t)(nt+ty+i)*K + kt+tx] = f2bf(tile[tx][ty+i]);
}

// ---------------- QKV GEMM (m97-style global_load_lds staging) --------------
__global__ __launch_bounds__(256) void qkv_gemm(
    const unsigned short* __restrict__ Xb, const unsigned short* __restrict__ Wt,
    const float* __restrict__ bias,
    unsigned short* __restrict__ Qb, unsigned short* __restrict__ Kb,
    unsigned short* __restrict__ Vt)
{
  __shared__ __align__(16) unsigned short As[128][32];
  __shared__ __align__(16) unsigned short Bs[128][32];
  const int tid = threadIdx.x;
  const int m0 = blockIdx.y*128, n0 = blockIdx.x*128;
  const int wv = tid>>6, lane = tid&63, lm = lane&15, lq = lane>>4;
  const int wr = wv>>1, wc = wv&1;
  f32x4 acc[4][4] = {};
  const int schunk = (lane&3) ^ ((lane>>3)&3);
  const unsigned short* gA = Xb + (size_t)(m0 + wv*32 + (lane>>2))*C_ + schunk*8;
  const unsigned short* gB = Wt + (size_t)(n0 + wv*32 + (lane>>2))*C_ + schunk*8;
  unsigned short* lA0 = &As[wv*32][0];
  unsigned short* lA1 = &As[wv*32+16][0];
  unsigned short* lB0 = &Bs[wv*32][0];
  unsigned short* lB1 = &Bs[wv*32+16][0];
  const int rkey = (lm>>1)&3;
  for (int k0=0;k0<C_;k0+=32){
    __syncthreads();
    gload_lds16(gA + k0,            lA0);
    gload_lds16(gA + 16*C_ + k0,    lA1);
    gload_lds16(gB + k0,            lB0);
    gload_lds16(gB + 16*C_ + k0,    lB1);
    __syncthreads();
    bf16x8 a[4], b[4];
    #pragma unroll
    for (int mt=0;mt<4;mt++) a[mt] = *(const bf16x8*)&As[wr*64+mt*16+lm][(lq^rkey)*8];
    #pragma unroll
    for (int nt=0;nt<4;nt++) b[nt] = *(const bf16x8*)&Bs[wc*64+nt*16+lm][(lq^rkey)*8];
    #pragma unroll
    for (int mt=0;mt<4;mt++)
      #pragma unroll
      for (int nt=0;nt<4;nt++)
        acc[mt][nt] = __builtin_amdgcn_mfma_f32_16x16x32_bf16(a[mt], b[nt], acc[mt][nt], 0,0,0);
  }
  const int sel = n0>>10;  // block-uniform: 0=Q,1=K,2=V
  const float qsc = (sel==0) ? 0.18033688f : 1.0f;  // 0.125*log2(e) folded into Q
  #pragma unroll
  for (int mt=0;mt<4;mt++){
    const int grow = m0 + wr*64 + mt*16 + lq*4;
    const int bb = grow>>11, tt0 = grow&2047;
    #pragma unroll
    for (int nt=0;nt<4;nt++){
      const int gcol = n0 + wc*64 + nt*16 + lm;
      const int hh = (gcol>>6)&15, dd = gcol&63;
      const float bv = bias[gcol];
      if (sel==2){
        ushort4 pv;
        pv.x = f2bf(acc[mt][nt][0] + bv);
        pv.y = f2bf(acc[mt][nt][1] + bv);
        pv.z = f2bf(acc[mt][nt][2] + bv);
        pv.w = f2bf(acc[mt][nt][3] + bv);
        *(ushort4*)&Vt[ ((size_t)(bb*H_+hh)*D_ + dd)*T_ + tt0 ] = pv;
      } else {
        unsigned short* dst = (sel==0) ? Qb : Kb;
        #pragma unroll
        for (int r=0;r<4;r++)
          dst[ ((size_t)(bb*H_+hh)*T_ + tt0 + r)*D_ + dd ] = f2bf((acc[mt][nt][r] + bv)*qsc);
      }
    }
  }
}

// ---------------- flash attention -------------------------------------------
// Double-buffered async K/V staging (DMA issued one iter ahead), dedicated
// swizzled P buffer -> ONE barrier per iteration; O computed transposed.
// Grid flat 2048: bh = id&63 (XCD L2 locality), qi = 31-(id>>6) (heavy first).
__global__ __launch_bounds__(256, 4) void flash_attn(
    const unsigned short* __restrict__ Qb, const unsigned short* __restrict__ Kb,
    const unsigned short* __restrict__ Vt, unsigned short* __restrict__ Yb)
{
  __shared__ __align__(16) unsigned short Ks[2][64][64]; // swizzled chunks
  __shared__ __align__(16) unsigned short Vs[2][64][64]; // V^T, swizzled
  __shared__ __align__(16) unsigned short Ps[64][64];    // P, swizzled, wave-local rows
  const int tid = threadIdx.x;
  const int wv = tid>>6, lane = tid&63, lm = lane&15, lq = lane>>4;
  const int id = (int)blockIdx.x;
  const int bh = id & 63;
  const int qi = 31 - (id >> 6);
  const int qbase = qi*64;
  const unsigned short* Qh = Qb + (size_t)bh*T_*D_;
  const unsigned short* Kh = Kb + (size_t)bh*T_*D_;
  const unsigned short* Vh = Vt + (size_t)bh*D_*T_;
  bf16x8 aq[2];
  {
    const int q = qbase + wv*16 + lm;
    aq[0] = *(const bf16x8*)&Qh[(size_t)q*D_ + lq*8];
    aq[1] = *(const bf16x8*)&Qh[(size_t)q*D_ + 32 + lq*8];
  }
  f32x4 o[4] = {};
  float l_r[4] = {0.f,0.f,0.f,0.f};
  // staging: wave wv covers rows [wv*16, wv*16+16) in two 8-row DMA issues;
  // lane -> row wv*16 + 8*is + (lane>>3), stored chunk lane&7,
  // source chunk (lane&7)^(row&7)
  const int srl = lane>>3;
  const int sc  = (lane&7) ^ srl;
  const unsigned short* kg = Kh + (size_t)(wv*16 + srl)*D_ + sc*8;
  const unsigned short* vg = Vh + (size_t)(wv*16 + srl)*T_ + sc*8;
  const int keyR = lm&7;   // read swizzle key for LDS rows ...*16+lm
  // issue DMA for tile 0 into buffer 0
  {
    unsigned short* lk = &Ks[0][wv*16][0];
    unsigned short* lv = &Vs[0][wv*16][0];
    gload_lds16(kg,            lk);
    gload_lds16(kg + 8*D_,     lk + 8*64);
    gload_lds16(vg,            lv);
    gload_lds16(vg + 8*T_,     lv + 8*64);
  }
  for (int j=0;j<=qi;j++){
    const int cb = j&1;
    __syncthreads();   // drains this wave's DMA (tile j) + prev-iter LDS reads;
                       // makes tile j visible to all waves
    if (j < qi){       // prefetch tile j+1 into the other buffer (hidden)
      unsigned short* lk = &Ks[cb^1][wv*16][0];
      unsigned short* lv = &Vs[cb^1][wv*16][0];
      gload_lds16(kg + (size_t)((j+1)*64  )*D_, lk);
      gload_lds16(kg + (size_t)((j+1)*64+8)*D_, lk + 8*64);
      gload_lds16(vg + (j+1)*64,                lv);
      gload_lds16(vg + 8*T_ + (j+1)*64,         lv + 8*64);
    }
    // S = Q K^T  (per wave: 16 q rows x 64 keys)
    f32x4 s[4] = {};
    #pragma unroll
    for (int nt=0;nt<4;nt++){
      bf16x8 bk0 = *(const bf16x8*)&Ks[cb][nt*16+lm][((lq  )^keyR)*8];
      bf16x8 bk1 = *(const bf16x8*)&Ks[cb][nt*16+lm][((lq+4)^keyR)*8];
      s[nt] = __builtin_amdgcn_mfma_f32_16x16x32_bf16(aq[0], bk0, s[nt], 0,0,0);
      s[nt] = __builtin_amdgcn_mfma_f32_16x16x32_bf16(aq[1], bk1, s[nt], 0,0,0);
    }
    // p = exp2(s) (Q pre-scaled); causal mask only on diagonal tile
    if (j==qi){
      const int qrow0 = wv*16 + lq*4;
      #pragma unroll
      for (int nt=0;nt<4;nt++){
        const int col = nt*16+lm;
        #pragma unroll
        for (int r=0;r<4;r++)
          s[nt][r] = (col <= qrow0+r) ? exp2f(s[nt][r]) : 0.f;
      }
    } else {
      #pragma unroll
      for (int nt=0;nt<4;nt++)
        #pragma unroll
        for (int r=0;r<4;r++)
          s[nt][r] = exp2f(s[nt][r]);
    }
    #pragma unroll
    for (int r=0;r<4;r++)
      l_r[r] += (s[0][r]+s[1][r]) + (s[2][r]+s[3][r]);
    // P -> dedicated LDS (C layout, swizzled chunks); rows wave-local -> no barrier
    #pragma unroll
    for (int nt=0;nt<4;nt++)
      #pragma unroll
      for (int r=0;r<4;r++){
        const int row = wv*16 + lq*4 + r;
        const int ch  = (2*nt + (lm>>3)) ^ (row&7);
        Ps[row][ch*8 + (lm&7)] = f2bf(s[nt][r]);
      }
    // O^T += V^T P^T : mfma(A=V-frag, B=P-frag) -> D[m=d][n=q]
    #pragma unroll
    for (int kc=0;kc<2;kc++){
      bf16x8 ap = *(const bf16x8*)&Ps[wv*16+lm][((kc*4+lq)^keyR)*8];
      #pragma unroll
      for (int dt=0;dt<4;dt++){
        bf16x8 bv = *(const bf16x8*)&Vs[cb][dt*16+lm][((kc*4+lq)^keyR)*8];
        o[dt] = __builtin_amdgcn_mfma_f32_16x16x32_bf16(bv, ap, o[dt], 0,0,0);
      }
    }
  }
  // l: reduce across 16 lm-lanes, then broadcast to transposed layout (q=lm)
  #pragma unroll
  for (int r=0;r<4;r++){
    float rs = l_r[r];
    rs += __shfl_xor(rs,1); rs += __shfl_xor(rs,2);
    rs += __shfl_xor(rs,4); rs += __shfl_xor(rs,8);
    l_r[r] = rs;
  }
  const int srcl = (lm>>2)<<4;  // lane holding row q=lm
  float lv0v = __shfl(l_r[0], srcl);
  float lv1v = __shfl(l_r[1], srcl);
  float lv2v = __shfl(l_r[2], srcl);
  float lv3v = __shfl(l_r[3], srcl);
  const int rr = lm&3;
  float linv = (rr==0) ? lv0v : (rr==1) ? lv1v : (rr==2) ? lv2v : lv3v;
  linv = 1.0f/linv;
  const int bb = bh>>4, hh = bh&15;
  const int q = qbase + wv*16 + lm;
  #pragma unroll
  for (int dt=0;dt<4;dt++){
    ushort4 y;
    y.x = f2bf(o[dt][0]*linv);
    y.y = f2bf(o[dt][1]*linv);
    y.z = f2bf(o[dt][2]*linv);
    y.w = f2bf(o[dt][3]*linv);
    *(ushort4*)&Yb[ ((size_t)bb*T_ + q)*C_ + hh*64 + dt*16 + lq*4 ] = y;
  }
}

// ---------------- proj GEMM (m97-style): Yb x Wpt^T -> fp32 out + bias ------
__global__ __launch_bounds__(256) void proj_gemm(
    const unsigned short* __restrict__ Yb, const unsigned short* __restrict__ Wt,
    const float* __restrict__ bias, float* __restrict__ Out)
{
  __shared__ __align__(16) unsigned short As[128][32];
  __shared__ __align__(16) unsigned short Bs[128][32];
  const int tid = threadIdx.x;
  const int m0 = blockIdx.y*128, n0 = blockIdx.x*128;
  const int wv = tid>>6, lane = tid&63, lm = lane&15, lq = lane>>4;
  const int wr = wv>>1, wc = wv&1;
  f32x4 acc[4][4] = {};
  const int schunk = (lane&3) ^ ((lane>>3)&3);
  const unsigned short* gA = Yb + (size_t)(m0 + wv*32 + (lane>>2))*C_ + schunk*8;
  const unsigned short* gB = Wt + (size_t)(n0 + wv*32 + (lane>>2))*C_ + schunk*8;
  unsigned short* lA0 = &As[wv*32][0];
  unsigned short* lA1 = &As[wv*32+16][0];
  unsigned short* lB0 = &Bs[wv*32][0];
  unsigned short* lB1 = &Bs[wv*32+16][0];
  const int rkey = (lm>>1)&3;
  for (int k0=0;k0<C_;k0+=32){
    __syncthreads();
    gload_lds16(gA + k0,            lA0);
    gload_lds16(gA + 16*C_ + k0,    lA1);
    gload_lds16(gB + k0,            lB0);
    gload_lds16(gB + 16*C_ + k0,    lB1);
    __syncthreads();
    bf16x8 a[4], b[4];
    #pragma unroll
    for (int mt=0;mt<4;mt++) a[mt] = *(const bf16x8*)&As[wr*64+mt*16+lm][(lq^rkey)*8];
    #pragma unroll
    for (int nt=0;nt<4;nt++) b[nt] = *(const bf16x8*)&Bs[wc*64+nt*16+lm][(lq^rkey)*8];
    #pragma unroll
    for (int mt=0;mt<4;mt++)
      #pragma unroll
      for (int nt=0;nt<4;nt++)
        acc[mt][nt] = __builtin_amdgcn_mfma_f32_16x16x32_bf16(a[mt], b[nt], acc[mt][nt], 0,0,0);
  }
  #pragma unroll
  for (int mt=0;mt<4;mt++){
    const int grow = m0 + wr*64 + mt*16 + lq*4;
    #pragma unroll
    for (int nt=0;nt<4;nt++){
      const int gcol = n0 + wc*64 + nt*16 + lm;
      const float bv = bias[gcol];
      #pragma unroll
      for (int r=0;r<4;r++)
        Out[(size_t)(grow+r)*C_ + gcol] = acc[mt][nt][r] + bv;
    }
  }
}

extern "C" void kernel_launch(void* const* d_in, const int* in_sizes, int n_in,
                              void* d_out, int out_size, void* d_ws, size_t ws_size,
                              hipStream_t stream)
{
  const float* x      = (const float*)d_in[0];
  const float* W_attn = (const float*)d_in[1];
  const float* b_attn = (const float*)d_in[2];
  const float* W_proj = (const float*)d_in[3];
  const float* b_proj = (const float*)d_in[4];
  float* out = (float*)d_out;

  unsigned short* Wat = (unsigned short*)d_ws;            // [3072][1024] bf16
  unsigned short* Wpt = Wat + (size_t)N3_*C_;             // [1024][1024] bf16
  unsigned short* Xb  = Wpt + (size_t)C_*C_;              // [M,1024]  bf16
  unsigned short* Qb  = Xb  + (size_t)M_*C_;              // [B,H,T,D] bf16 (pre-scaled)
  unsigned short* Kb  = Qb  + (size_t)M_*C_;              // [B,H,T,D] bf16
  unsigned short* Vt  = Kb  + (size_t)M_*C_;              // [B,H,D,T] bf16
  unsigned short* Yb  = Vt  + (size_t)M_*C_;              // [M,1024]  bf16
  (void)ws_size; (void)in_sizes; (void)n_in; (void)out_size;

  x_cvt        <<<dim3(M_*C_/2048),      256, 0, stream>>>(x, Xb);
  transpose_cvt<<<dim3(N3_/32, C_/32),   256, 0, stream>>>(W_attn, Wat, C_, N3_);
  transpose_cvt<<<dim3(C_/32,  C_/32),   256, 0, stream>>>(W_proj, Wpt, C_, C_);
  qkv_gemm     <<<dim3(N3_/128, M_/128), 256, 0, stream>>>(Xb, Wat, b_attn, Qb, Kb, Vt);
  flash_attn   <<<dim3(2048),            256, 0, stream>>>(Qb, Kb, Vt, Yb);
  proj_gemm    <<<dim3(C_/128, M_/128),  256, 0, stream>>>(Yb, Wpt, b_proj, out);
}